// Round 10
// baseline (280.587 us; speedup 1.0000x reference)
//
#include <hip/hip_runtime.h>
#include <hip/hip_fp16.h>

#define IN_F 128
#define HID_F 64
#define OUT_F 8

// Bucketed CSR build: bucket = dst >> 7 (128 nodes/bucket).
#define BSHIFT 7
#define BGRAN 128
#define BCAP 2688
#define NBUK_MAX 784
#define CHUNK 4096
#define EPT (CHUNK / 256)
#define CEPT ((BCAP + 255) / 256)

typedef _Float16 f16x8 __attribute__((ext_vector_type(8)));
typedef float f32x4 __attribute__((ext_vector_type(4)));

// ---------------------------------------------------------------------------
// init_bcur: bucket cursors at fixed-capacity bases.
// ---------------------------------------------------------------------------
__global__ __launch_bounds__(1024) void init_bcur(int* __restrict__ bcur, int nbuk) {
  int t = threadIdx.x;
  if (t < nbuk) bcur[t] = t * BCAP;
}

// ---------------------------------------------------------------------------
// bucket_scatter: per-chunk LDS histogram -> one global reserve per bucket ->
// write PACKED edges (dstLocal<<24 | src) grouped by bucket.
// ---------------------------------------------------------------------------
__global__ __launch_bounds__(256) void bucket_scatter(
    const int* __restrict__ src, const int* __restrict__ dst,
    int* __restrict__ bcur, int* __restrict__ ebuf, int n_edges) {
  __shared__ int hist[NBUK_MAX];
  __shared__ int base[NBUK_MAX];
  int t = threadIdx.x;
  for (int i = t; i < NBUK_MAX; i += 256) hist[i] = 0;
  __syncthreads();
  int e0 = blockIdx.x * CHUNK;
  int pk[EPT];
  int bk[EPT];
#pragma unroll
  for (int k = 0; k < EPT; ++k) {
    int e = e0 + k * 256 + t;
    if (e < n_edges) {
      int s = src[e];
      int d = dst[e];
      bk[k] = d >> BSHIFT;
      pk[k] = ((d & (BGRAN - 1)) << 24) | s;
      atomicAdd(&hist[bk[k]], 1);
    } else {
      bk[k] = -1;
    }
  }
  __syncthreads();
  for (int i = t; i < NBUK_MAX; i += 256) {
    int c = hist[i];
    base[i] = c ? atomicAdd(&bcur[i], c) : 0;
  }
  __syncthreads();
  for (int i = t; i < NBUK_MAX; i += 256) hist[i] = 0;
  __syncthreads();
#pragma unroll
  for (int k = 0; k < EPT; ++k) {
    if (bk[k] >= 0) {
      int r = atomicAdd(&hist[bk[k]], 1);
      ebuf[base[bk[k]] + r] = pk[k];
    }
  }
}

// ---------------------------------------------------------------------------
// bucket_csr: counting-sort of each bucket's edges entirely in LDS.
// offs_f[node] = bucket_base + local_prefix (per-bucket fixed-capacity runs).
// ---------------------------------------------------------------------------
__global__ __launch_bounds__(256) void bucket_csr(
    const int* __restrict__ ebuf, const int* __restrict__ bcur,
    int* __restrict__ offs_f, int* __restrict__ deg_i,
    int* __restrict__ csr_src, int n_nodes) {
  __shared__ int hist[BGRAN];
  __shared__ int cur[BGRAN];
  __shared__ int s[BGRAN];
  __shared__ int lds_src[BCAP];
  int b = blockIdx.x;
  int t = threadIdx.x;
  if (t < BGRAN) hist[t] = 0;
  __syncthreads();
  int beg = b * BCAP;
  int cnt = bcur[b] - beg;
  int pk[CEPT];
  int np = 0;
  for (int j = t; j < cnt; j += 256) {
    pk[np] = ebuf[beg + j];
    atomicAdd(&hist[(unsigned)pk[np] >> 24], 1);
    ++np;
  }
  __syncthreads();
  if (t < BGRAN) s[t] = hist[t];
  __syncthreads();
  for (int d = 1; d < BGRAN; d <<= 1) {
    int v = 0;
    if (t >= d && t < BGRAN) v = s[t - d];
    __syncthreads();
    if (t >= d && t < BGRAN) s[t] += v;
    __syncthreads();
  }
  if (t < BGRAN) {
    int excl = (t == 0) ? 0 : s[t - 1];
    cur[t] = excl;
    int node = b * BGRAN + t;
    if (node < n_nodes) {
      offs_f[node] = beg + excl;
      deg_i[node] = hist[t];
    }
  }
  __syncthreads();
  for (int i = 0; i < np; ++i) {
    int dl = (unsigned)pk[i] >> 24;
    int p = atomicAdd(&cur[dl], 1);
    lds_src[p] = pk[i] & 0xFFFFFF;
  }
  __syncthreads();
  for (int j = t; j < cnt; j += 256) csr_src[beg + j] = lds_src[j];
}

// ---------------------------------------------------------------------------
// w_prep: transpose [W1_l | W1_r] (fp32, k-major) -> Wt f16 [128 n][128 k]
// (n-major, contiguous k) for direct MFMA B-fragment loads. 32 KB total.
// ---------------------------------------------------------------------------
__global__ __launch_bounds__(128) void w_prep(
    const float* __restrict__ Wl, const float* __restrict__ Wr,
    _Float16* __restrict__ Wt) {
  int n = threadIdx.x;   // 0..127 output column
  for (int k = 0; k < IN_F; ++k) {
    float v = (n < HID_F) ? Wl[k * HID_F + n] : Wr[k * HID_F + (n - HID_F)];
    Wt[n * IN_F + k] = (_Float16)v;
  }
}

// ---------------------------------------------------------------------------
// k1_proj (MFMA): [n x 128] @ [128 x 128] via mfma_f32_16x16x32_f16.
// Block = 64 nodes, 4 waves; wave w computes rows w*16..+15 x all 128 cols
// (8 col-tiles). x tile staged in LDS as f16 (row stride 136 to de-conflict);
// B-frags straight from global Wt (L2-resident). Epilogue: C/D layout
// col=lane&15, row=quad*4+reg. Also packs dropout mask -> 1 bit/feature.
// ---------------------------------------------------------------------------
#define K1_ROWS 64
#define XSTRIDE 136
__global__ __launch_bounds__(256) void k1_proj(
    const float* __restrict__ x,
    const _Float16* __restrict__ Wt,
    const float* __restrict__ b1,
    const float* __restrict__ mask,
    __half* __restrict__ y1h,
    __half* __restrict__ r1h,
    unsigned long long* __restrict__ mbits,
    int n_nodes) {
  __shared__ _Float16 XS[K1_ROWS * XSTRIDE];   // 17 KB
  int tid = threadIdx.x;
  int w = tid >> 6;
  int lane = tid & 63;
  int n0 = blockIdx.x * K1_ROWS;

  // dropout mask bit-pack: wave w handles 16 nodes; lane = feature.
  for (int i = w * 16; i < w * 16 + 16; ++i) {
    int node = n0 + i;
    if (node < n_nodes) {
      float mv = mask[(size_t)node * HID_F + lane];
      unsigned long long bits = __ballot(mv > 0.5f);
      if (lane == 0) mbits[node] = bits;
    }
  }

  // stage x tile -> LDS f16: 64 rows x 128 k (2048 float4 loads)
#pragma unroll
  for (int p = 0; p < 8; ++p) {
    int i = tid + p * 256;          // float4 slot: row = i>>5, k4 = (i&31)*4
    int row = i >> 5;
    int k4 = (i & 31) * 4;
    int gs = min(n0 + row, n_nodes - 1);
    float4 v = *(const float4*)(x + (size_t)gs * IN_F + k4);
    _Float16 hv[4] = {(_Float16)v.x, (_Float16)v.y, (_Float16)v.z, (_Float16)v.w};
    *(uint2*)&XS[row * XSTRIDE + k4] = *(uint2*)hv;
  }
  __syncthreads();

  int m = lane & 15;        // row within wave tile / col within C tile
  int quad = lane >> 4;     // k-subrange selector (A/B), row-quad (C/D)

  f32x4 acc[8];
#pragma unroll
  for (int t = 0; t < 8; ++t) acc[t] = f32x4{0.f, 0.f, 0.f, 0.f};

#pragma unroll
  for (int kk = 0; kk < 4; ++kk) {
    f16x8 a = *(const f16x8*)&XS[(w * 16 + m) * XSTRIDE + kk * 32 + quad * 8];
#pragma unroll
    for (int t = 0; t < 8; ++t) {
      f16x8 b = *(const f16x8*)(Wt + ((size_t)(t * 16 + m) * IN_F) + kk * 32 + quad * 8);
      acc[t] = __builtin_amdgcn_mfma_f32_16x16x32_f16(a, b, acc[t], 0, 0, 0);
    }
  }

  // bias for the r-half (cols 64..127): col = t*16 + m
  float bb[4];
#pragma unroll
  for (int t = 4; t < 8; ++t) bb[t - 4] = b1[(t - 4) * 16 + m];

  // epilogue: lane holds rows quad*4+r (r=0..3) of col m in each col-tile t
#pragma unroll
  for (int t = 0; t < 8; ++t) {
    bool isR = (t >= 4);
    int col = isR ? (t - 4) * 16 + m : t * 16 + m;
    __half* dbuf = isR ? r1h : y1h;
    float badd = isR ? bb[t - 4] : 0.f;
#pragma unroll
    for (int r = 0; r < 4; ++r) {
      int node = n0 + w * 16 + quad * 4 + r;
      if (node < n_nodes)
        dbuf[(size_t)node * HID_F + col] = __float2half(acc[t][r] + badd);
    }
  }
}

// ---------------------------------------------------------------------------
// agg1_fused: one wave per dst node; quad-edge uint2 gathers (16 edges in
// flight). fp16 r1, bitmask dropout, fp16 h output.
// ---------------------------------------------------------------------------
__global__ __launch_bounds__(256) void agg1_fused(
    const __half* __restrict__ y1h,
    const __half* __restrict__ r1h,
    const int* __restrict__ deg_i,
    const int* __restrict__ offs,
    const int* __restrict__ csr_src,
    const unsigned long long* __restrict__ mbits,
    __half* __restrict__ h_h,
    int n_nodes) {
  int node = (blockIdx.x * blockDim.x + threadIdx.x) >> 6;
  int lane = threadIdx.x & 63;
  if (node >= n_nodes) return;
  int q = lane >> 4;
  int f4 = lane & 15;
  int beg = offs[node];
  int d = deg_i[node];
  const int* cp = csr_src + beg;
  float a0 = 0.f, a1 = 0.f, a2 = 0.f, a3 = 0.f;
  int j = 0;
  for (; j + 16 <= d; j += 16) {
    int s0 = cp[j + q];
    int s1 = cp[j + 4 + q];
    int s2 = cp[j + 8 + q];
    int s3 = cp[j + 12 + q];
    uint2 g0 = *(const uint2*)(y1h + (size_t)s0 * HID_F + f4 * 4);
    uint2 g1 = *(const uint2*)(y1h + (size_t)s1 * HID_F + f4 * 4);
    uint2 g2 = *(const uint2*)(y1h + (size_t)s2 * HID_F + f4 * 4);
    uint2 g3 = *(const uint2*)(y1h + (size_t)s3 * HID_F + f4 * 4);
    float2 p0 = __half22float2(*(const __half2*)&g0.x);
    float2 p1 = __half22float2(*(const __half2*)&g0.y);
    float2 p2 = __half22float2(*(const __half2*)&g1.x);
    float2 p3 = __half22float2(*(const __half2*)&g1.y);
    float2 p4 = __half22float2(*(const __half2*)&g2.x);
    float2 p5 = __half22float2(*(const __half2*)&g2.y);
    float2 p6 = __half22float2(*(const __half2*)&g3.x);
    float2 p7 = __half22float2(*(const __half2*)&g3.y);
    a0 += (p0.x + p2.x) + (p4.x + p6.x);
    a1 += (p0.y + p2.y) + (p4.y + p6.y);
    a2 += (p1.x + p3.x) + (p5.x + p7.x);
    a3 += (p1.y + p3.y) + (p5.y + p7.y);
  }
  for (; j < d; j += 4) {
    int e = j + q;
    if (e < d) {
      int s = cp[e];
      uint2 g = *(const uint2*)(y1h + (size_t)s * HID_F + f4 * 4);
      float2 p0 = __half22float2(*(const __half2*)&g.x);
      float2 p1 = __half22float2(*(const __half2*)&g.y);
      a0 += p0.x; a1 += p0.y; a2 += p1.x; a3 += p1.y;
    }
  }
  a0 += __shfl_xor(a0, 16); a0 += __shfl_xor(a0, 32);
  a1 += __shfl_xor(a1, 16); a1 += __shfl_xor(a1, 32);
  a2 += __shfl_xor(a2, 16); a2 += __shfl_xor(a2, 32);
  a3 += __shfl_xor(a3, 16); a3 += __shfl_xor(a3, 32);
  if (q == 0) {
    float inv = 1.0f / fmaxf((float)d, 1.0f);
    size_t o = (size_t)node * HID_F + f4 * 4;
    uint2 rg = *(const uint2*)(r1h + o);
    float2 r01 = __half22float2(*(const __half2*)&rg.x);
    float2 r23 = __half22float2(*(const __half2*)&rg.y);
    unsigned long long mb = mbits[node];
    float vx = fmaxf(a0 * inv + r01.x, 0.f);
    float vy = fmaxf(a1 * inv + r01.y, 0.f);
    float vz = fmaxf(a2 * inv + r23.x, 0.f);
    float vw = fmaxf(a3 * inv + r23.y, 0.f);
    int fb = f4 * 4;
    vx = ((mb >> (fb + 0)) & 1ull) ? vx * 2.f : 0.f;
    vy = ((mb >> (fb + 1)) & 1ull) ? vy * 2.f : 0.f;
    vz = ((mb >> (fb + 2)) & 1ull) ? vz * 2.f : 0.f;
    vw = ((mb >> (fb + 3)) & 1ull) ? vw * 2.f : 0.f;
    __half hh[4] = {__float2half(vx), __float2half(vy),
                    __float2half(vz), __float2half(vw)};
    *(uint2*)(h_h + o) = *(uint2*)hh;
  }
}

// ---------------------------------------------------------------------------
// k3b: z = h @ W2_l ([N,8] fp16). h fp16 in, W2_l in LDS.
// ---------------------------------------------------------------------------
__global__ __launch_bounds__(256) void k3b_z(
    const __half* __restrict__ h_h,
    const float* __restrict__ W2l,
    __half* __restrict__ z,
    int n_nodes) {
  __shared__ float WS[HID_F][OUT_F];
  int tid = threadIdx.x;
  if (tid < 128) {
    float4 w = *(const float4*)(W2l + tid * 4);
    *(float4*)&WS[tid >> 1][(tid & 1) * 4] = w;
  }
  __syncthreads();
  int node = blockIdx.x * blockDim.x + tid;
  if (node >= n_nodes) return;
  const __half* hr = h_h + (size_t)node * HID_F;
  float acc[8] = {0, 0, 0, 0, 0, 0, 0, 0};
  for (int k = 0; k < HID_F; k += 8) {
    uint4 hv = *(const uint4*)(hr + k);
    float2 f0 = __half22float2(*(const __half2*)&hv.x);
    float2 f1 = __half22float2(*(const __half2*)&hv.y);
    float2 f2 = __half22float2(*(const __half2*)&hv.z);
    float2 f3 = __half22float2(*(const __half2*)&hv.w);
    float hh[8] = {f0.x, f0.y, f1.x, f1.y, f2.x, f2.y, f3.x, f3.y};
#pragma unroll
    for (int j = 0; j < 8; ++j) {
      float4 w0 = *(const float4*)&WS[k + j][0];
      float4 w1 = *(const float4*)&WS[k + j][4];
      acc[0] += hh[j] * w0.x; acc[1] += hh[j] * w0.y;
      acc[2] += hh[j] * w0.z; acc[3] += hh[j] * w0.w;
      acc[4] += hh[j] * w1.x; acc[5] += hh[j] * w1.y;
      acc[6] += hh[j] * w1.z; acc[7] += hh[j] * w1.w;
    }
  }
  __half hz[8];
#pragma unroll
  for (int j = 0; j < 8; ++j) hz[j] = __float2half(acc[j]);
  *(uint4*)(z + (size_t)node * OUT_F) = *(uint4*)hz;
}

// ---------------------------------------------------------------------------
// out_fused: one wave per batch element; layer-2 agg only at idx nodes.
// ---------------------------------------------------------------------------
__global__ __launch_bounds__(256) void out_fused(
    const int* __restrict__ idx,
    const __half* __restrict__ z,
    const int* __restrict__ deg_i,
    const int* __restrict__ offs,
    const int* __restrict__ csr_src,
    const __half* __restrict__ h_h,
    const float* __restrict__ W2r,
    const float* __restrict__ b2,
    float* __restrict__ out,
    int n_batch) {
  int b = (blockIdx.x * blockDim.x + threadIdx.x) >> 6;
  int lane = threadIdx.x & 63;
  if (b >= n_batch) return;
  int i = idx[b];
  int e8 = lane >> 3;
  int o = lane & 7;
  int beg = offs[i];
  int d = deg_i[i];
  float acc = 0.f;
  for (int j = e8; j < d; j += 8) {
    int s = csr_src[beg + j];
    acc += __half2float(z[(size_t)s * OUT_F + o]);
  }
  float dv = fmaxf((float)d, 1.0f);
  float v = acc / dv;
  uint4 hv = *(const uint4*)(h_h + (size_t)i * HID_F + e8 * 8);
  float2 f0 = __half22float2(*(const __half2*)&hv.x);
  float2 f1 = __half22float2(*(const __half2*)&hv.y);
  float2 f2 = __half22float2(*(const __half2*)&hv.z);
  float2 f3 = __half22float2(*(const __half2*)&hv.w);
  float hh[8] = {f0.x, f0.y, f1.x, f1.y, f2.x, f2.y, f3.x, f3.y};
#pragma unroll
  for (int jj = 0; jj < 8; ++jj) {
    int k = e8 * 8 + jj;
    v += hh[jj] * W2r[k * OUT_F + o];
  }
  v += __shfl_xor(v, 8);
  v += __shfl_xor(v, 16);
  v += __shfl_xor(v, 32);
  if (e8 == 0) out[(size_t)b * OUT_F + o] = v + b2[o];
}

extern "C" void kernel_launch(void* const* d_in, const int* in_sizes, int n_in,
                              void* d_out, int out_size, void* d_ws, size_t ws_size,
                              hipStream_t stream) {
  const float* x    = (const float*)d_in[0];
  const int*   ei   = (const int*)d_in[1];
  const int*   idx  = (const int*)d_in[2];
  const float* mask = (const float*)d_in[3];
  const float* W1l  = (const float*)d_in[4];
  const float* W1r  = (const float*)d_in[5];
  const float* b1   = (const float*)d_in[6];
  const float* W2l  = (const float*)d_in[7];
  const float* W2r  = (const float*)d_in[8];
  const float* b2   = (const float*)d_in[9];
  float* out = (float*)d_out;

  int n_nodes = in_sizes[0] / IN_F;
  int n_edges = in_sizes[1] / 2;
  int n_batch = in_sizes[2];
  const int* src = ei;
  const int* dst = ei + n_edges;

  int nbuk = (n_nodes + BGRAN - 1) / BGRAN;   // 782
  int nchunk = (n_edges + CHUNK - 1) / CHUNK; // 391

  // workspace
  char* ws = (char*)d_ws;
  size_t off = 0;
  __half* y1h = (__half*)(ws + off); off += (size_t)n_nodes * HID_F * 2;
  __half* r1h = (__half*)(ws + off); off += (size_t)n_nodes * HID_F * 2;
  __half* h_h = (__half*)(ws + off); off += (size_t)n_nodes * HID_F * 2;
  __half* z   = (__half*)(ws + off); off += (size_t)n_nodes * OUT_F * 2;
  unsigned long long* mbits = (unsigned long long*)(ws + off); off += (size_t)n_nodes * 8;
  _Float16* Wt = (_Float16*)(ws + off); off += (size_t)IN_F * IN_F * 2;
  int* ebuf    = (int*)(ws + off); off += (size_t)nbuk * BCAP * 4;
  int* csr_src = (int*)(ws + off); off += (size_t)nbuk * BCAP * 4;
  int* deg_i   = (int*)(ws + off); off += (size_t)n_nodes * 4;
  int* offs_f  = (int*)(ws + off); off += (size_t)n_nodes * 4;
  int* bcur    = (int*)(ws + off); off += NBUK_MAX * 4;

  // --- CSR build + weight prep ---
  init_bcur<<<1, 1024, 0, stream>>>(bcur, nbuk);
  w_prep<<<1, 128, 0, stream>>>(W1l, W1r, Wt);
  bucket_scatter<<<nchunk, 256, 0, stream>>>(src, dst, bcur, ebuf, n_edges);
  // k1 (MFMA) between build stages
  k1_proj<<<(n_nodes + K1_ROWS - 1) / K1_ROWS, 256, 0, stream>>>(
      x, Wt, b1, mask, y1h, r1h, mbits, n_nodes);
  bucket_csr<<<nbuk, 256, 0, stream>>>(ebuf, bcur, offs_f, deg_i, csr_src, n_nodes);

  // --- layer 1 aggregation ---
  {
    long long th = (long long)n_nodes * HID_F;
    agg1_fused<<<(int)((th + 255) / 256), 256, 0, stream>>>(
        y1h, r1h, deg_i, offs_f, csr_src, mbits, h_h, n_nodes);
  }

  // --- layer 2 ---
  k3b_z<<<(n_nodes + 255) / 256, 256, 0, stream>>>(h_h, W2l, z, n_nodes);
  {
    long long th = (long long)n_batch * 64;
    out_fused<<<(int)((th + 255) / 256), 256, 0, stream>>>(
        idx, z, deg_i, offs_f, csr_src, h_h, W2r, b2, out, n_batch);
  }
}

// Round 11
// 257.005 us; speedup vs baseline: 1.0918x; 1.0918x over previous
//
#include <hip/hip_runtime.h>
#include <hip/hip_fp16.h>

#define IN_F 128
#define HID_F 64
#define OUT_F 8

// Bucketed CSR build: bucket = dst >> 7 (128 nodes/bucket).
#define BSHIFT 7
#define BGRAN 128
#define BCAP 2688
#define NBUK_MAX 784
#define CHUNK 4096
#define EPT (CHUNK / 256)
#define CEPT ((BCAP + 255) / 256)

typedef _Float16 f16x8 __attribute__((ext_vector_type(8)));
typedef float f32x4 __attribute__((ext_vector_type(4)));

// ---------------------------------------------------------------------------
// init_bcur: bucket cursors at fixed-capacity bases.
// ---------------------------------------------------------------------------
__global__ __launch_bounds__(1024) void init_bcur(int* __restrict__ bcur, int nbuk) {
  int t = threadIdx.x;
  if (t < nbuk) bcur[t] = t * BCAP;
}

// ---------------------------------------------------------------------------
// bucket_scatter: per-chunk LDS histogram -> one global reserve per bucket ->
// write PACKED edges (dstLocal<<24 | src) grouped by bucket.
// ---------------------------------------------------------------------------
__global__ __launch_bounds__(256) void bucket_scatter(
    const int* __restrict__ src, const int* __restrict__ dst,
    int* __restrict__ bcur, int* __restrict__ ebuf, int n_edges) {
  __shared__ int hist[NBUK_MAX];
  __shared__ int base[NBUK_MAX];
  int t = threadIdx.x;
  for (int i = t; i < NBUK_MAX; i += 256) hist[i] = 0;
  __syncthreads();
  int e0 = blockIdx.x * CHUNK;
  int pk[EPT];
  int bk[EPT];
#pragma unroll
  for (int k = 0; k < EPT; ++k) {
    int e = e0 + k * 256 + t;
    if (e < n_edges) {
      int s = src[e];
      int d = dst[e];
      bk[k] = d >> BSHIFT;
      pk[k] = ((d & (BGRAN - 1)) << 24) | s;
      atomicAdd(&hist[bk[k]], 1);
    } else {
      bk[k] = -1;
    }
  }
  __syncthreads();
  for (int i = t; i < NBUK_MAX; i += 256) {
    int c = hist[i];
    base[i] = c ? atomicAdd(&bcur[i], c) : 0;
  }
  __syncthreads();
  for (int i = t; i < NBUK_MAX; i += 256) hist[i] = 0;
  __syncthreads();
#pragma unroll
  for (int k = 0; k < EPT; ++k) {
    if (bk[k] >= 0) {
      int r = atomicAdd(&hist[bk[k]], 1);
      ebuf[base[bk[k]] + r] = pk[k];
    }
  }
}

// ---------------------------------------------------------------------------
// bucket_csr: counting-sort of each bucket's edges entirely in LDS.
// ---------------------------------------------------------------------------
__global__ __launch_bounds__(256) void bucket_csr(
    const int* __restrict__ ebuf, const int* __restrict__ bcur,
    int* __restrict__ offs_f, int* __restrict__ deg_i,
    int* __restrict__ csr_src, int n_nodes) {
  __shared__ int hist[BGRAN];
  __shared__ int cur[BGRAN];
  __shared__ int s[BGRAN];
  __shared__ int lds_src[BCAP];
  int b = blockIdx.x;
  int t = threadIdx.x;
  if (t < BGRAN) hist[t] = 0;
  __syncthreads();
  int beg = b * BCAP;
  int cnt = bcur[b] - beg;
  int pk[CEPT];
  int np = 0;
  for (int j = t; j < cnt; j += 256) {
    pk[np] = ebuf[beg + j];
    atomicAdd(&hist[(unsigned)pk[np] >> 24], 1);
    ++np;
  }
  __syncthreads();
  if (t < BGRAN) s[t] = hist[t];
  __syncthreads();
  for (int d = 1; d < BGRAN; d <<= 1) {
    int v = 0;
    if (t >= d && t < BGRAN) v = s[t - d];
    __syncthreads();
    if (t >= d && t < BGRAN) s[t] += v;
    __syncthreads();
  }
  if (t < BGRAN) {
    int excl = (t == 0) ? 0 : s[t - 1];
    cur[t] = excl;
    int node = b * BGRAN + t;
    if (node < n_nodes) {
      offs_f[node] = beg + excl;
      deg_i[node] = hist[t];
    }
  }
  __syncthreads();
  for (int i = 0; i < np; ++i) {
    int dl = (unsigned)pk[i] >> 24;
    int p = atomicAdd(&cur[dl], 1);
    lds_src[p] = pk[i] & 0xFFFFFF;
  }
  __syncthreads();
  for (int j = t; j < cnt; j += 256) csr_src[beg + j] = lds_src[j];
}

// ---------------------------------------------------------------------------
// w_prep: transpose [W1_l | W1_r] (fp32, k-major) -> Wt f16 [128 n][128 k].
// ---------------------------------------------------------------------------
__global__ __launch_bounds__(128) void w_prep(
    const float* __restrict__ Wl, const float* __restrict__ Wr,
    _Float16* __restrict__ Wt) {
  int n = threadIdx.x;
  for (int k = 0; k < IN_F; ++k) {
    float v = (n < HID_F) ? Wl[k * HID_F + n] : Wr[k * HID_F + (n - HID_F)];
    Wt[n * IN_F + k] = (_Float16)v;
  }
}

// ---------------------------------------------------------------------------
// k1_proj (MFMA, operand-swapped): A = W frag (hoisted to regs ONCE, 8 frags
// = 32 VGPR), B = X frag from LDS. D layout: col=lane&15 -> NODE, row=
// quad*4+reg -> 4 consecutive output cols => contiguous 8B epilogue stores.
// Block = 128 nodes x 4 waves; wave w covers col-tiles {w (y-half), w+4
// (r-half)} for all 8 row-tiles. No global load inside the MFMA loop.
// ---------------------------------------------------------------------------
#define K1_ROWS 128
#define XSH 136   // halves per XS row (pad: 2-way bank aliasing only)
__global__ __launch_bounds__(256) void k1_proj(
    const float* __restrict__ x,
    const _Float16* __restrict__ Wt,
    const float* __restrict__ b1,
    const float* __restrict__ mask,
    __half* __restrict__ y1h,
    __half* __restrict__ r1h,
    unsigned long long* __restrict__ mbits,
    int n_nodes) {
  __shared__ _Float16 XS[K1_ROWS * XSH];   // 34816 B
  int tid = threadIdx.x;
  int w = tid >> 6;
  int lane = tid & 63;
  int n0 = blockIdx.x * K1_ROWS;
  int m = lane & 15;
  int quad = lane >> 4;

  // dropout mask bit-pack: wave w handles nodes w*32 .. w*32+31
  for (int i = w * 32; i < w * 32 + 32; ++i) {
    int node = n0 + i;
    if (node < n_nodes) {
      float mv = mask[(size_t)node * HID_F + lane];
      unsigned long long bits = __ballot(mv > 0.5f);
      if (lane == 0) mbits[node] = bits;
    }
  }

  // hoist W fragments (A-operand) into registers once: t = w and w+4
  f16x8 af[2][4];
#pragma unroll
  for (int ti = 0; ti < 2; ++ti) {
    int t = w + ti * 4;
#pragma unroll
    for (int kk = 0; kk < 4; ++kk)
      af[ti][kk] = *(const f16x8*)(Wt + (size_t)(t * 16 + m) * IN_F + kk * 32 + quad * 8);
  }
  float4 b1v = *(const float4*)(b1 + w * 16 + quad * 4);

  // stage x tile -> LDS f16: 128 rows x 128 k
#pragma unroll
  for (int p = 0; p < 16; ++p) {
    int i = tid + p * 256;          // row = i>>5, k4 = (i&31)*4
    int row = i >> 5;
    int k4 = (i & 31) * 4;
    int gs = min(n0 + row, n_nodes - 1);
    float4 v = *(const float4*)(x + (size_t)gs * IN_F + k4);
    _Float16 hv[4] = {(_Float16)v.x, (_Float16)v.y, (_Float16)v.z, (_Float16)v.w};
    *(uint2*)&XS[row * XSH + k4] = *(uint2*)hv;
  }
  __syncthreads();

#pragma unroll
  for (int rt = 0; rt < 8; ++rt) {
    f32x4 acc0 = f32x4{0.f, 0.f, 0.f, 0.f};
    f32x4 acc1 = f32x4{0.f, 0.f, 0.f, 0.f};
#pragma unroll
    for (int kk = 0; kk < 4; ++kk) {
      f16x8 bx = *(const f16x8*)&XS[(rt * 16 + m) * XSH + kk * 32 + quad * 8];
      acc0 = __builtin_amdgcn_mfma_f32_16x16x32_f16(af[0][kk], bx, acc0, 0, 0, 0);
      acc1 = __builtin_amdgcn_mfma_f32_16x16x32_f16(af[1][kk], bx, acc1, 0, 0, 0);
    }
    int node = n0 + rt * 16 + m;
    if (node < n_nodes) {
      __half hy[4], hr[4];
#pragma unroll
      for (int r = 0; r < 4; ++r) {
        hy[r] = __float2half(acc0[r]);
        hr[r] = __float2half(acc1[r] + ((const float*)&b1v)[r]);
      }
      *(uint2*)(y1h + (size_t)node * HID_F + w * 16 + quad * 4) = *(uint2*)hy;
      *(uint2*)(r1h + (size_t)node * HID_F + w * 16 + quad * 4) = *(uint2*)hr;
    }
  }
}

// ---------------------------------------------------------------------------
// agg1_fused: one wave per dst node; quad-edge uint2 gathers (16 edges in
// flight). fp16 r1, bitmask dropout, fp16 h output.
// ---------------------------------------------------------------------------
__global__ __launch_bounds__(256) void agg1_fused(
    const __half* __restrict__ y1h,
    const __half* __restrict__ r1h,
    const int* __restrict__ deg_i,
    const int* __restrict__ offs,
    const int* __restrict__ csr_src,
    const unsigned long long* __restrict__ mbits,
    __half* __restrict__ h_h,
    int n_nodes) {
  int node = (blockIdx.x * blockDim.x + threadIdx.x) >> 6;
  int lane = threadIdx.x & 63;
  if (node >= n_nodes) return;
  int q = lane >> 4;
  int f4 = lane & 15;
  int beg = offs[node];
  int d = deg_i[node];
  const int* cp = csr_src + beg;
  float a0 = 0.f, a1 = 0.f, a2 = 0.f, a3 = 0.f;
  int j = 0;
  for (; j + 16 <= d; j += 16) {
    int s0 = cp[j + q];
    int s1 = cp[j + 4 + q];
    int s2 = cp[j + 8 + q];
    int s3 = cp[j + 12 + q];
    uint2 g0 = *(const uint2*)(y1h + (size_t)s0 * HID_F + f4 * 4);
    uint2 g1 = *(const uint2*)(y1h + (size_t)s1 * HID_F + f4 * 4);
    uint2 g2 = *(const uint2*)(y1h + (size_t)s2 * HID_F + f4 * 4);
    uint2 g3 = *(const uint2*)(y1h + (size_t)s3 * HID_F + f4 * 4);
    float2 p0 = __half22float2(*(const __half2*)&g0.x);
    float2 p1 = __half22float2(*(const __half2*)&g0.y);
    float2 p2 = __half22float2(*(const __half2*)&g1.x);
    float2 p3 = __half22float2(*(const __half2*)&g1.y);
    float2 p4 = __half22float2(*(const __half2*)&g2.x);
    float2 p5 = __half22float2(*(const __half2*)&g2.y);
    float2 p6 = __half22float2(*(const __half2*)&g3.x);
    float2 p7 = __half22float2(*(const __half2*)&g3.y);
    a0 += (p0.x + p2.x) + (p4.x + p6.x);
    a1 += (p0.y + p2.y) + (p4.y + p6.y);
    a2 += (p1.x + p3.x) + (p5.x + p7.x);
    a3 += (p1.y + p3.y) + (p5.y + p7.y);
  }
  for (; j < d; j += 4) {
    int e = j + q;
    if (e < d) {
      int s = cp[e];
      uint2 g = *(const uint2*)(y1h + (size_t)s * HID_F + f4 * 4);
      float2 p0 = __half22float2(*(const __half2*)&g.x);
      float2 p1 = __half22float2(*(const __half2*)&g.y);
      a0 += p0.x; a1 += p0.y; a2 += p1.x; a3 += p1.y;
    }
  }
  a0 += __shfl_xor(a0, 16); a0 += __shfl_xor(a0, 32);
  a1 += __shfl_xor(a1, 16); a1 += __shfl_xor(a1, 32);
  a2 += __shfl_xor(a2, 16); a2 += __shfl_xor(a2, 32);
  a3 += __shfl_xor(a3, 16); a3 += __shfl_xor(a3, 32);
  if (q == 0) {
    float inv = 1.0f / fmaxf((float)d, 1.0f);
    size_t o = (size_t)node * HID_F + f4 * 4;
    uint2 rg = *(const uint2*)(r1h + o);
    float2 r01 = __half22float2(*(const __half2*)&rg.x);
    float2 r23 = __half22float2(*(const __half2*)&rg.y);
    unsigned long long mb = mbits[node];
    float vx = fmaxf(a0 * inv + r01.x, 0.f);
    float vy = fmaxf(a1 * inv + r01.y, 0.f);
    float vz = fmaxf(a2 * inv + r23.x, 0.f);
    float vw = fmaxf(a3 * inv + r23.y, 0.f);
    int fb = f4 * 4;
    vx = ((mb >> (fb + 0)) & 1ull) ? vx * 2.f : 0.f;
    vy = ((mb >> (fb + 1)) & 1ull) ? vy * 2.f : 0.f;
    vz = ((mb >> (fb + 2)) & 1ull) ? vz * 2.f : 0.f;
    vw = ((mb >> (fb + 3)) & 1ull) ? vw * 2.f : 0.f;
    __half hh[4] = {__float2half(vx), __float2half(vy),
                    __float2half(vz), __float2half(vw)};
    *(uint2*)(h_h + o) = *(uint2*)hh;
  }
}

// ---------------------------------------------------------------------------
// k3b: z = h @ W2_l ([N,8] fp16). h fp16 in, W2_l in LDS.
// ---------------------------------------------------------------------------
__global__ __launch_bounds__(256) void k3b_z(
    const __half* __restrict__ h_h,
    const float* __restrict__ W2l,
    __half* __restrict__ z,
    int n_nodes) {
  __shared__ float WS[HID_F][OUT_F];
  int tid = threadIdx.x;
  if (tid < 128) {
    float4 w = *(const float4*)(W2l + tid * 4);
    *(float4*)&WS[tid >> 1][(tid & 1) * 4] = w;
  }
  __syncthreads();
  int node = blockIdx.x * blockDim.x + tid;
  if (node >= n_nodes) return;
  const __half* hr = h_h + (size_t)node * HID_F;
  float acc[8] = {0, 0, 0, 0, 0, 0, 0, 0};
  for (int k = 0; k < HID_F; k += 8) {
    uint4 hv = *(const uint4*)(hr + k);
    float2 f0 = __half22float2(*(const __half2*)&hv.x);
    float2 f1 = __half22float2(*(const __half2*)&hv.y);
    float2 f2 = __half22float2(*(const __half2*)&hv.z);
    float2 f3 = __half22float2(*(const __half2*)&hv.w);
    float hh[8] = {f0.x, f0.y, f1.x, f1.y, f2.x, f2.y, f3.x, f3.y};
#pragma unroll
    for (int j = 0; j < 8; ++j) {
      float4 w0 = *(const float4*)&WS[k + j][0];
      float4 w1 = *(const float4*)&WS[k + j][4];
      acc[0] += hh[j] * w0.x; acc[1] += hh[j] * w0.y;
      acc[2] += hh[j] * w0.z; acc[3] += hh[j] * w0.w;
      acc[4] += hh[j] * w1.x; acc[5] += hh[j] * w1.y;
      acc[6] += hh[j] * w1.z; acc[7] += hh[j] * w1.w;
    }
  }
  __half hz[8];
#pragma unroll
  for (int j = 0; j < 8; ++j) hz[j] = __float2half(acc[j]);
  *(uint4*)(z + (size_t)node * OUT_F) = *(uint4*)hz;
}

// ---------------------------------------------------------------------------
// out_fused: one wave per batch element; layer-2 agg only at idx nodes.
// ---------------------------------------------------------------------------
__global__ __launch_bounds__(256) void out_fused(
    const int* __restrict__ idx,
    const __half* __restrict__ z,
    const int* __restrict__ deg_i,
    const int* __restrict__ offs,
    const int* __restrict__ csr_src,
    const __half* __restrict__ h_h,
    const float* __restrict__ W2r,
    const float* __restrict__ b2,
    float* __restrict__ out,
    int n_batch) {
  int b = (blockIdx.x * blockDim.x + threadIdx.x) >> 6;
  int lane = threadIdx.x & 63;
  if (b >= n_batch) return;
  int i = idx[b];
  int e8 = lane >> 3;
  int o = lane & 7;
  int beg = offs[i];
  int d = deg_i[i];
  float acc = 0.f;
  for (int j = e8; j < d; j += 8) {
    int s = csr_src[beg + j];
    acc += __half2float(z[(size_t)s * OUT_F + o]);
  }
  float dv = fmaxf((float)d, 1.0f);
  float v = acc / dv;
  uint4 hv = *(const uint4*)(h_h + (size_t)i * HID_F + e8 * 8);
  float2 f0 = __half22float2(*(const __half2*)&hv.x);
  float2 f1 = __half22float2(*(const __half2*)&hv.y);
  float2 f2 = __half22float2(*(const __half2*)&hv.z);
  float2 f3 = __half22float2(*(const __half2*)&hv.w);
  float hh[8] = {f0.x, f0.y, f1.x, f1.y, f2.x, f2.y, f3.x, f3.y};
#pragma unroll
  for (int jj = 0; jj < 8; ++jj) {
    int k = e8 * 8 + jj;
    v += hh[jj] * W2r[k * OUT_F + o];
  }
  v += __shfl_xor(v, 8);
  v += __shfl_xor(v, 16);
  v += __shfl_xor(v, 32);
  if (e8 == 0) out[(size_t)b * OUT_F + o] = v + b2[o];
}

extern "C" void kernel_launch(void* const* d_in, const int* in_sizes, int n_in,
                              void* d_out, int out_size, void* d_ws, size_t ws_size,
                              hipStream_t stream) {
  const float* x    = (const float*)d_in[0];
  const int*   ei   = (const int*)d_in[1];
  const int*   idx  = (const int*)d_in[2];
  const float* mask = (const float*)d_in[3];
  const float* W1l  = (const float*)d_in[4];
  const float* W1r  = (const float*)d_in[5];
  const float* b1   = (const float*)d_in[6];
  const float* W2l  = (const float*)d_in[7];
  const float* W2r  = (const float*)d_in[8];
  const float* b2   = (const float*)d_in[9];
  float* out = (float*)d_out;

  int n_nodes = in_sizes[0] / IN_F;
  int n_edges = in_sizes[1] / 2;
  int n_batch = in_sizes[2];
  const int* src = ei;
  const int* dst = ei + n_edges;

  int nbuk = (n_nodes + BGRAN - 1) / BGRAN;   // 782
  int nchunk = (n_edges + CHUNK - 1) / CHUNK; // 391

  // workspace
  char* ws = (char*)d_ws;
  size_t off = 0;
  __half* y1h = (__half*)(ws + off); off += (size_t)n_nodes * HID_F * 2;
  __half* r1h = (__half*)(ws + off); off += (size_t)n_nodes * HID_F * 2;
  __half* h_h = (__half*)(ws + off); off += (size_t)n_nodes * HID_F * 2;
  __half* z   = (__half*)(ws + off); off += (size_t)n_nodes * OUT_F * 2;
  unsigned long long* mbits = (unsigned long long*)(ws + off); off += (size_t)n_nodes * 8;
  _Float16* Wt = (_Float16*)(ws + off); off += (size_t)IN_F * IN_F * 2;
  int* ebuf    = (int*)(ws + off); off += (size_t)nbuk * BCAP * 4;
  int* csr_src = (int*)(ws + off); off += (size_t)nbuk * BCAP * 4;
  int* deg_i   = (int*)(ws + off); off += (size_t)n_nodes * 4;
  int* offs_f  = (int*)(ws + off); off += (size_t)n_nodes * 4;
  int* bcur    = (int*)(ws + off); off += NBUK_MAX * 4;

  // --- CSR build + weight prep ---
  init_bcur<<<1, 1024, 0, stream>>>(bcur, nbuk);
  w_prep<<<1, 128, 0, stream>>>(W1l, W1r, Wt);
  bucket_scatter<<<nchunk, 256, 0, stream>>>(src, dst, bcur, ebuf, n_edges);
  // k1 (MFMA) between build stages
  k1_proj<<<(n_nodes + K1_ROWS - 1) / K1_ROWS, 256, 0, stream>>>(
      x, Wt, b1, mask, y1h, r1h, mbits, n_nodes);
  bucket_csr<<<nbuk, 256, 0, stream>>>(ebuf, bcur, offs_f, deg_i, csr_src, n_nodes);

  // --- layer 1 aggregation ---
  {
    long long th = (long long)n_nodes * HID_F;
    agg1_fused<<<(int)((th + 255) / 256), 256, 0, stream>>>(
        y1h, r1h, deg_i, offs_f, csr_src, mbits, h_h, n_nodes);
  }

  // --- layer 2 ---
  k3b_z<<<(n_nodes + 255) / 256, 256, 0, stream>>>(h_h, W2l, z, n_nodes);
  {
    long long th = (long long)n_batch * 64;
    out_fused<<<(int)((th + 255) / 256), 256, 0, stream>>>(
        idx, z, deg_i, offs_f, csr_src, h_h, W2r, b2, out, n_batch);
  }
}